// Round 5
// baseline (198.877 us; speedup 1.0000x reference)
//
#include <hip/hip_runtime.h>

// QNN closed form: q_b = prod_{i<8} cos(pi/2 + 2*x_bi) = prod_{i<8} sin(2*x_bi)
// (8 negative signs cancel). out[b,0] = s*q, out[b,1] = -s*q.
//
// Two-rows-per-thread scheme (round 3): thread t owns rows 2t and 2t+1.
// It issues FOUR independent global_load_dwordx4 (64 B/lane in flight) before
// any dependent compute — 2x the memory-level parallelism of the previous
// row-per-thread version, which rocprof showed was stuck at ~4.0 TB/s while
// pure-store fills hit 6.9 TB/s on the same chip (MLP shortfall, not issue
// rate: removing the shuffle in round 2 changed nothing). Output for both
// rows is fused into ONE float4 store {s*q0, -s*q0, s*q1, -s*q1} = 16 B/lane,
// 1 KiB/wave contiguous — the coalescing sweet spot.
//
// NOTE: in_sizes[] is in ELEMENTS, not bytes. in_sizes[0] = B*8 floats.

__global__ __launch_bounds__(256) void qnn_kernel(const float4* __restrict__ x4,
                                                  const float* __restrict__ scale_p,
                                                  float4* __restrict__ out4,
                                                  int npairs) {
    int t = blockIdx.x * blockDim.x + threadIdx.x;
    if (t >= npairs) return;

    // 4 independent 16B loads, issued before any dependent ALU.
    float4 a = x4[4 * t + 0];
    float4 b = x4[4 * t + 1];
    float4 c = x4[4 * t + 2];
    float4 d = x4[4 * t + 3];

    // __sinf: v_mul (1/2pi) + v_sin_f32. |2x| <~ 12 rad for N(0,1) -> accurate.
    float q0 = __sinf(2.0f * a.x) * __sinf(2.0f * a.y) *
               __sinf(2.0f * a.z) * __sinf(2.0f * a.w) *
               __sinf(2.0f * b.x) * __sinf(2.0f * b.y) *
               __sinf(2.0f * b.z) * __sinf(2.0f * b.w);
    float q1 = __sinf(2.0f * c.x) * __sinf(2.0f * c.y) *
               __sinf(2.0f * c.z) * __sinf(2.0f * c.w) *
               __sinf(2.0f * d.x) * __sinf(2.0f * d.y) *
               __sinf(2.0f * d.z) * __sinf(2.0f * d.w);

    float s = scale_p[0];
    out4[t] = make_float4(s * q0, -s * q0, s * q1, -s * q1);
}

extern "C" void kernel_launch(void* const* d_in, const int* in_sizes, int n_in,
                              void* d_out, int out_size, void* d_ws, size_t ws_size,
                              hipStream_t stream) {
    const float4* x4    = (const float4*)d_in[0];   // [B,8] fp32 viewed as [B*2] float4
    const float*  scale = (const float*)d_in[2];    // scalar (d_in[1] = weights, unused)
    float4*       out4  = (float4*)d_out;           // [B,2] fp32 = B/2 float4

    int npairs = in_sizes[0] / 16;                  // element count: B*8 floats -> B/2 row-pairs
    int block = 256;
    int grid = (npairs + block - 1) / block;        // B/2 = 2,097,152 -> 8192 blocks, no tail
    qnn_kernel<<<grid, block, 0, stream>>>(x4, scale, out4, npairs);
}